// Round 6
// baseline (122.730 us; speedup 1.0000x reference)
//
#include <hip/hip_runtime.h>

#define LSZ 512
#define CCH 4
#define NLAY 4
#define TILE 64
#define HALO 8
#define RG 80        // region size = TILE + 2*HALO

typedef float v2f __attribute__((ext_vector_type(2)));

// Packed fp32 math (VOP3P). Component-wise IEEE fp32 — bitwise-symmetry
// argument identical to scalar.
__device__ __forceinline__ v2f pk_add(v2f a, v2f b) {
    v2f d; asm("v_pk_add_f32 %0, %1, %2" : "=v"(d) : "v"(a), "v"(b)); return d;
}
__device__ __forceinline__ v2f pk_mul(v2f a, v2f b) {
    v2f d; asm("v_pk_mul_f32 %0, %1, %2" : "=v"(d) : "v"(a), "v"(b)); return d;
}
__device__ __forceinline__ v2f pk_fma(v2f a, v2f b, v2f c) {
    v2f d; asm("v_pk_fma_f32 %0, %1, %2, %3" : "=v"(d) : "v"(a), "v"(b), "v"(c)); return d;
}
__device__ __forceinline__ v2f celu2(v2f y) {
    v2f r;
    r.x = y.x >= 0.0f ? y.x : __expf(y.x) - 1.0f;
    r.y = y.y >= 0.0f ? y.y : __expf(y.y) - 1.0f;
    return r;
}
#define LO2(v) ((v2f){(v).x, (v).y})
#define HI2(v) ((v2f){(v).z, (v).w})

// One workgroup per (b, c, upper-triangular 64x64 tile).
// g built from n on the fly; 4 stencil layers IN PLACE in one 80x80 LDS buffer.
// R6: sites are 2 rows x 4 cols (j % 4 == 0) so ALL LDS traffic is ds_read_b128/
// ds_write_b128: 10 reads + 2 writes = 192 B per 8 outputs (24 B/output vs 32).
// Edge sites blend new/old per element so writes stay full b128. All shifted
// horizontal reads stay in-bounds (sites at i=0/78 are never active; j-edges
// read adjacent-row garbage that only feeds blended-away lanes).
__global__ __launch_bounds__(256, 4) void stencil_kernel(
    const float* __restrict__ nn,
    const float* __restrict__ w_self,
    const float* __restrict__ w_nbr,
    float* __restrict__ sep)
{
    __shared__ __align__(16) float buf[RG * RG];
    __shared__ float nrow[RG][3];
    __shared__ float ncol[RG][3];

    const int tid = threadIdx.x;
    const int bid = blockIdx.x;
    const int img = bid / 36;           // 36 upper-tri tiles per (b,c) image
    int t = bid - img * 36;
    const int b = img >> 2;
    const int c = img & 3;
    int ti = 0;
    while (t >= 8 - ti) { t -= 8 - ti; ti++; }
    const int tj = ti + t;
    const int gi0 = ti * TILE;
    const int gj0 = tj * TILE;
    const int dd = (gj0 - gi0) & (LSZ - 1);   // diag when (i-j-dd) % 512 == 0
    const bool tile_masked = (dd == 0) || (dd == 64) || (dd == 448);

    // ---- load n rows & cols (with halo, cyclic wrap) ----
    for (int u = tid; u < RG * 3 * 2; u += 256) {
        int which = u >= RG * 3;
        int v = which ? u - RG * 3 : u;
        int rr = v / 3, d = v - 3 * rr;
        int base = which ? gj0 : gi0;
        int gl = (base - HALO + rr) & (LSZ - 1);
        float val = nn[(b * LSZ + gl) * 3 + d];
        if (which) ncol[rr][d] = val; else nrow[rr][d] = val;
    }

    // ---- per-thread sites: 800 = 40 rows (i=2*ri) x 20 cols (j=4*sj) ----
    int ofs[4], iv[4], jv[4];
#pragma unroll
    for (int it = 0; it < 4; it++) {
        int s = tid + 256 * it;
        if (s < 800) {
            int ri = s / 20;
            int sj = s - 20 * ri;
            iv[it] = 2 * ri;
            jv[it] = 4 * sj;
            ofs[it] = iv[it] * RG + jv[it];
        } else { ofs[it] = -1; iv[it] = 0; jv[it] = 0; }
    }
    __syncthreads();

    // ---- build g (Gram matrix, zero diagonal), 2x4 blocks, b128 stores ----
#pragma unroll
    for (int it = 0; it < 4; it++) {
        if (ofs[it] < 0) continue;
        int i = iv[it], j = jv[it];
        float r00 = nrow[i][0],   r01 = nrow[i][1],   r02 = nrow[i][2];
        float r10 = nrow[i+1][0], r11 = nrow[i+1][1], r12 = nrow[i+1][2];
        float4 g0, g1;
        {   float c0 = ncol[j][0],   c1 = ncol[j][1],   c2 = ncol[j][2];
            g0.x = r00*c0 + r01*c1 + r02*c2;  g1.x = r10*c0 + r11*c1 + r12*c2; }
        {   float c0 = ncol[j+1][0], c1 = ncol[j+1][1], c2 = ncol[j+1][2];
            g0.y = r00*c0 + r01*c1 + r02*c2;  g1.y = r10*c0 + r11*c1 + r12*c2; }
        {   float c0 = ncol[j+2][0], c1 = ncol[j+2][1], c2 = ncol[j+2][2];
            g0.z = r00*c0 + r01*c1 + r02*c2;  g1.z = r10*c0 + r11*c1 + r12*c2; }
        {   float c0 = ncol[j+3][0], c1 = ncol[j+3][1], c2 = ncol[j+3][2];
            g0.w = r00*c0 + r01*c1 + r02*c2;  g1.w = r10*c0 + r11*c1 + r12*c2; }
        if (tile_masked) {
            int E = (i - j - dd) & 511;        // row i: zero col E if E<4
            int F = (E + 1) & 511;             // row i+1: zero col F if F<4
            g0.x = (E==0)?0.0f:g0.x; g0.y = (E==1)?0.0f:g0.y;
            g0.z = (E==2)?0.0f:g0.z; g0.w = (E==3)?0.0f:g0.w;
            g1.x = (F==0)?0.0f:g1.x; g1.y = (F==1)?0.0f:g1.y;
            g1.z = (F==2)?0.0f:g1.z; g1.w = (F==3)?0.0f:g1.w;
        }
        *(float4*)&buf[ofs[it]]      = g0;
        *(float4*)&buf[ofs[it] + RG] = g1;
    }
    __syncthreads();

    // ---- 4 stencil layers, in place: compute->regs, barrier, write, barrier ----
    for (int ell = 0; ell < NLAY; ell++) {
        const float ws  = w_self[c * NLAY + ell];
        const float wn1 = w_nbr[(c * NLAY + ell) * 2 + 0];
        const float wn2 = w_nbr[(c * NLAY + ell) * 2 + 1];
        const v2f ws2 = (v2f){ws,  ws};
        const v2f w12 = (v2f){wn1, wn1};
        const v2f w22 = (v2f){wn2, wn2};
        const int pad = 2 * (ell + 1);
        const int lim = 79 - pad;
        float4 so0[4], so1[4];
        int act[4];
#pragma unroll
        for (int it = 0; it < 4; it++) {
            int i = iv[it], j = jv[it];
            act[it] = (ofs[it] >= 0) &&
                      (min(min(i + 1, 79 - i), min(j + 3, 79 - j)) >= pad);
            if (!act[it]) continue;
            const float* P = buf + ofs[it];
            float4 RM2 = *(const float4*)(P - 2*RG);   // row i-2, cols j..j+3
            float4 RM1 = *(const float4*)(P -   RG);   // row i-1
            float4 A0  = *(const float4*)(P - 4);      // row i,   cols j-4..j-1
            float4 B0  = *(const float4*)(P);          // row i,   cols j..j+3
            float4 C0  = *(const float4*)(P + 4);      // row i,   cols j+4..j+7
            float4 A1  = *(const float4*)(P + RG - 4); // row i+1
            float4 B1  = *(const float4*)(P + RG);
            float4 C1  = *(const float4*)(P + RG + 4);
            float4 RP2 = *(const float4*)(P + 2*RG);   // row i+2
            float4 RP3 = *(const float4*)(P + 3*RG);   // row i+3

            // ---- row i (outputs cols j..j+3) ----
            v2f bL = LO2(B0), bH = HI2(B0);
            v2f m0  = (v2f){B0.y, B0.z};
            v2f s1L = pk_add((v2f){A0.w, B0.x}, m0);          // l1+r1 lo
            v2f s1H = pk_add(m0, (v2f){B0.w, C0.x});          // l1+r1 hi
            v2f s2L = pk_add(HI2(A0), bH);                    // l2+r2 lo (free halves)
            v2f s2H = pk_add(bL, LO2(C0));                    // l2+r2 hi
            v2f v1L = pk_add(LO2(RM1), LO2(B1));              // u1+d1
            v2f v1H = pk_add(HI2(RM1), HI2(B1));
            v2f v2L = pk_add(LO2(RM2), LO2(RP2));             // u2+d2
            v2f v2H = pk_add(HI2(RM2), HI2(RP2));
            // (l+r)+(u+d) grouping -> bitwise equal at transpose site
            v2f y0L = pk_fma(ws2, bL, pk_fma(w12, pk_add(s1L, v1L),
                                     pk_mul(w22, pk_add(s2L, v2L))));
            v2f y0H = pk_fma(ws2, bH, pk_fma(w12, pk_add(s1H, v1H),
                                     pk_mul(w22, pk_add(s2H, v2H))));
            v2f x0L = pk_add(bL, celu2(y0L));
            v2f x0H = pk_add(bH, celu2(y0H));

            // ---- row i+1 ----
            v2f cL = LO2(B1), cH = HI2(B1);
            v2f m1  = (v2f){B1.y, B1.z};
            v2f t1L = pk_add((v2f){A1.w, B1.x}, m1);
            v2f t1H = pk_add(m1, (v2f){B1.w, C1.x});
            v2f t2L = pk_add(HI2(A1), cH);
            v2f t2H = pk_add(cL, LO2(C1));
            v2f w1L = pk_add(bL, LO2(RP2));                   // u1+d1
            v2f w1H = pk_add(bH, HI2(RP2));
            v2f w2L = pk_add(LO2(RM1), LO2(RP3));             // u2+d2
            v2f w2H = pk_add(HI2(RM1), HI2(RP3));
            v2f y1L = pk_fma(ws2, cL, pk_fma(w12, pk_add(t1L, w1L),
                                     pk_mul(w22, pk_add(t2L, w2L))));
            v2f y1H = pk_fma(ws2, cH, pk_fma(w12, pk_add(t1H, w1H),
                                     pk_mul(w22, pk_add(t2H, w2H))));
            v2f x1L = pk_add(cL, celu2(y1L));
            v2f x1H = pk_add(cH, celu2(y1H));

            float4 xn0 = {x0L.x, x0L.y, x0H.x, x0H.y};
            float4 xn1 = {x1L.x, x1L.y, x1H.x, x1H.y};
            if (tile_masked) {
                int E = (i - j - dd) & 511;
                int F = (E + 1) & 511;
                xn0.x = (E==0)?0.0f:xn0.x; xn0.y = (E==1)?0.0f:xn0.y;
                xn0.z = (E==2)?0.0f:xn0.z; xn0.w = (E==3)?0.0f:xn0.w;
                xn1.x = (F==0)?0.0f:xn1.x; xn1.y = (F==1)?0.0f:xn1.y;
                xn1.z = (F==2)?0.0f:xn1.z; xn1.w = (F==3)?0.0f:xn1.w;
            }
            bool fully = (i >= pad) && (i + 1 <= lim) && (j >= pad) && (j + 3 <= lim);
            if (!fully) {   // blend: keep old value at out-of-window elements
                bool r0 = (i >= pad)     && (i <= lim);
                bool r1 = (i + 1 >= pad) && (i + 1 <= lim);
                bool c0 = (j >= pad)     && (j <= lim);
                bool c1 = (j + 1 >= pad) && (j + 1 <= lim);
                bool c2 = (j + 2 >= pad) && (j + 2 <= lim);
                bool c3 = (j + 3 >= pad) && (j + 3 <= lim);
                xn0.x = (r0 && c0) ? xn0.x : B0.x;
                xn0.y = (r0 && c1) ? xn0.y : B0.y;
                xn0.z = (r0 && c2) ? xn0.z : B0.z;
                xn0.w = (r0 && c3) ? xn0.w : B0.w;
                xn1.x = (r1 && c0) ? xn1.x : B1.x;
                xn1.y = (r1 && c1) ? xn1.y : B1.y;
                xn1.z = (r1 && c2) ? xn1.z : B1.z;
                xn1.w = (r1 && c3) ? xn1.w : B1.w;
            }
            so0[it] = xn0;
            so1[it] = xn1;
        }
        __syncthreads();
#pragma unroll
        for (int it = 0; it < 4; it++) {
            if (!act[it]) continue;
            *(float4*)&buf[ofs[it]]      = so0[it];
            *(float4*)&buf[ofs[it] + RG] = so1[it];
        }
        __syncthreads();
    }
    // final x is in buf (core = region [8,72)^2)

    // ---- cyclic-diagonal reduction: 127 diagonals, 2 threads each ----
    if (tid < 254) {
        int dt = tid >> 1;
        int half = tid & 1;
        int delta = dt - 63;                 // j - i in [-63, 63]
        int ad = delta < 0 ? -delta : delta;
        int Nd = 64 - ad;
        int i0 = 8 + (delta < 0 ? -delta : 0);
        int base = i0 * RG + (i0 + delta);
        float s = 0.0f;
        for (int k = half; k < Nd; k += 2)
            s += buf[base + k * (RG + 1)];
        s += __shfl_xor(s, 1);
        if (half == 0) {
            int r = (gj0 - gi0 + delta) & (LSZ - 1);
            float* sp = sep + (b * CCH + c) * LSZ;
            atomicAdd(sp + r, s);
            if (ti != tj)  // mirror contribution for the skipped transpose tile
                atomicAdd(sp + ((LSZ - r) & (LSZ - 1)), s);
        }
    }
}

// MLP stage 1 (unchanged from R5): partial[(b*32+ms)*256+k]
__global__ __launch_bounds__(256) void mlp1_kernel(
    const float* __restrict__ sep,
    const float* __restrict__ W1,
    float* __restrict__ partial)
{
    __shared__ float4 red[4][64];
    const int b  = blockIdx.x >> 5;
    const int ms = blockIdx.x & 31;
    const int kq = threadIdx.x & 63;
    const int mq = threadIdx.x >> 6;
    const int m0 = ms * 64 + mq * 16;
    const float* sv = sep + b * 2048 + m0;
    const float* w  = W1 + m0 * 256 + kq * 4;
    float4 a0 = {0,0,0,0}, a1 = {0,0,0,0};
#pragma unroll
    for (int m = 0; m < 16; m += 2) {
        float4 w0 = *(const float4*)(w + (m)     * 256);
        float4 w1 = *(const float4*)(w + (m + 1) * 256);
        float s0 = sv[m], s1 = sv[m + 1];
        a0.x += s0 * w0.x; a0.y += s0 * w0.y; a0.z += s0 * w0.z; a0.w += s0 * w0.w;
        a1.x += s1 * w1.x; a1.y += s1 * w1.y; a1.z += s1 * w1.z; a1.w += s1 * w1.w;
    }
    float4 a;
    a.x = a0.x + a1.x; a.y = a0.y + a1.y; a.z = a0.z + a1.z; a.w = a0.w + a1.w;
    red[mq][kq] = a;
    __syncthreads();
    if (mq == 0) {
        float4 r0 = red[0][kq], r1 = red[1][kq], r2 = red[2][kq], r3 = red[3][kq];
        float4 o;
        o.x = (r0.x + r1.x) + (r2.x + r3.x);
        o.y = (r0.y + r1.y) + (r2.y + r3.y);
        o.z = (r0.z + r1.z) + (r2.z + r3.z);
        o.w = (r0.w + r1.w) + (r2.w + r3.w);
        *(float4*)&partial[(b * 32 + ms) * 256 + kq * 4] = o;
    }
}

// MLP stage 2 (unchanged from R5)
__global__ __launch_bounds__(256) void mlp2_kernel(
    const float* __restrict__ partial,
    const float* __restrict__ b1,
    const float* __restrict__ W2,
    const float* __restrict__ b2,
    float* __restrict__ out)
{
    __shared__ double red[4];
    const int b = blockIdx.x;
    const int k = threadIdx.x;
    double s = 0;
#pragma unroll
    for (int p = 0; p < 32; p++)
        s += (double)partial[(b * 32 + p) * 256 + k];
    s += (double)b1[k];
    s = s >= 0.0 ? s : exp(s) - 1.0;          // celu
    double q = s * (double)W2[k];
    for (int off = 32; off >= 1; off >>= 1) q += __shfl_down(q, off);
    if ((k & 63) == 0) red[k >> 6] = q;
    __syncthreads();
    if (k == 0) {
        double y = ((red[0] + red[1]) + (red[2] + red[3])) + (double)b2[0];
        out[b] = (float)exp(-y);
    }
}

extern "C" void kernel_launch(void* const* d_in, const int* in_sizes, int n_in,
                              void* d_out, int out_size, void* d_ws, size_t ws_size,
                              hipStream_t stream) {
    const float* nn     = (const float*)d_in[0];
    const float* w_self = (const float*)d_in[1];
    const float* w_nbr  = (const float*)d_in[2];
    const float* W1     = (const float*)d_in[3];
    const float* b1     = (const float*)d_in[4];
    const float* W2     = (const float*)d_in[5];
    const float* b2     = (const float*)d_in[6];
    float* out = (float*)d_out;
    float* sep     = (float*)d_ws;                                  // 128 KB
    float* partial = (float*)((char*)d_ws + 16 * CCH * LSZ * sizeof(float)); // 512 KB

    hipMemsetAsync(sep, 0, 16 * CCH * LSZ * sizeof(float), stream);
    stencil_kernel<<<64 * 36, 256, 0, stream>>>(nn, w_self, w_nbr, sep);
    mlp1_kernel<<<512, 256, 0, stream>>>(sep, W1, partial);
    mlp2_kernel<<<16, 256, 0, stream>>>(partial, b1, W2, b2, out);
}

// Round 7
// 106.849 us; speedup vs baseline: 1.1486x; 1.1486x over previous
//
#include <hip/hip_runtime.h>

#define LSZ 512
#define CCH 4
#define NLAY 4
#define TILE 64
#define HALO 8
#define RG  80       // logical region size = TILE + 2*HALO
#define RGP 82       // LDS row pitch: even (b64-aligned), 82%32=18 spreads banks

typedef float v2f __attribute__((ext_vector_type(2)));

// Packed fp32 math (VOP3P). Component-wise IEEE fp32 — bitwise-symmetry
// argument identical to scalar.
__device__ __forceinline__ v2f pk_add(v2f a, v2f b) {
    v2f d; asm("v_pk_add_f32 %0, %1, %2" : "=v"(d) : "v"(a), "v"(b)); return d;
}
__device__ __forceinline__ v2f pk_mul(v2f a, v2f b) {
    v2f d; asm("v_pk_mul_f32 %0, %1, %2" : "=v"(d) : "v"(a), "v"(b)); return d;
}
__device__ __forceinline__ v2f pk_fma(v2f a, v2f b, v2f c) {
    v2f d; asm("v_pk_fma_f32 %0, %1, %2, %3" : "=v"(d) : "v"(a), "v"(b), "v"(c)); return d;
}
__device__ __forceinline__ v2f celu2(v2f y) {
    v2f r;
    r.x = y.x >= 0.0f ? y.x : __expf(y.x) - 1.0f;
    r.y = y.y >= 0.0f ? y.y : __expf(y.y) - 1.0f;
    return r;
}
// aligned 8B LDS load (even float index by construction)
__device__ __forceinline__ v2f ld2(const float* p) { return *(const v2f*)p; }

// One workgroup per (b, c, upper-triangular 64x64 tile).
// g built from n on the fly; 4 stencil layers IN PLACE in one 80-row x 82-pitch
// LDS buffer. R7: per 2x2 site exactly 10 aligned ds_read_b64 + 2 ds_write_b64
// (no ds_read2 — horizontal (l1+r1) pairs composed from register halves with
// scalar adds). Tiles with ti>tj skipped; contribution via mirror bin (512-r),
// valid because x stays bitwise-symmetric ((l+r)+(u+d) grouping commutes).
__global__ __launch_bounds__(256, 6) void stencil_kernel(
    const float* __restrict__ nn,
    const float* __restrict__ w_self,
    const float* __restrict__ w_nbr,
    float* __restrict__ sep)
{
    __shared__ __align__(16) float buf[RG * RGP];
    __shared__ float nrow[RG][3];
    __shared__ float ncol[RG][3];

    const int tid = threadIdx.x;
    const int bid = blockIdx.x;
    const int img = bid / 36;           // 36 upper-tri tiles per (b,c) image
    int t = bid - img * 36;
    const int b = img >> 2;
    const int c = img & 3;
    int ti = 0;
    while (t >= 8 - ti) { t -= 8 - ti; ti++; }
    const int tj = ti + t;
    const int gi0 = ti * TILE;
    const int gj0 = tj * TILE;
    const int dd = (gj0 - gi0) & (LSZ - 1);   // diag when (i-j-dd) % 512 == 0
    const bool tile_masked = (dd == 0) || (dd == 64) || (dd == 448);

    // ---- load n rows & cols (with halo, cyclic wrap) ----
    for (int u = tid; u < RG * 3 * 2; u += 256) {
        int which = u >= RG * 3;
        int v = which ? u - RG * 3 : u;
        int rr = v / 3, d = v - 3 * rr;
        int base = which ? gj0 : gi0;
        int gl = (base - HALO + rr) & (LSZ - 1);
        float val = nn[(b * LSZ + gl) * 3 + d];
        if (which) ncol[rr][d] = val; else nrow[rr][d] = val;
    }

    // ---- per-site precompute (2x2 blocks at even i,j; 1600 sites) ----
    int ofs[7];   // i*RGP + j, or -1 for empty slot
    int iv[7], jv[7];
    int ring[7];  // min(i, 78-i, j, 78-j); active at layer ell iff ring >= 2*(ell+1)
    int ew[7];    // (i-j-dd+1) & 511: 1 -> zero (0,0),(1,1); 2 -> (0,1); 0 -> (1,0)
#pragma unroll
    for (int it = 0; it < 7; it++) {
        int g = tid + 256 * it;
        if (g < 1600) {
            int gi2 = g / 40;
            int i = 2 * gi2, j = 2 * (g - 40 * gi2);
            iv[it] = i; jv[it] = j;
            ofs[it]  = i * RGP + j;
            ring[it] = min(min(i, 78 - i), min(j, 78 - j));
            ew[it]   = (i - j - dd + 1) & 511;
        } else { ofs[it] = -1; iv[it] = 0; jv[it] = 0; ring[it] = -1; ew[it] = 99; }
    }
    __syncthreads();

    // ---- build g (Gram matrix, zero diagonal), 2x2 blocks ----
#pragma unroll
    for (int it = 0; it < 7; it++) {
        if (ofs[it] < 0) continue;
        int i = iv[it], j = jv[it];
        float a00 = nrow[i][0],   a01 = nrow[i][1],   a02 = nrow[i][2];
        float a10 = nrow[i+1][0], a11 = nrow[i+1][1], a12 = nrow[i+1][2];
        float c00 = ncol[j][0],   c01 = ncol[j][1],   c02 = ncol[j][2];
        float c10 = ncol[j+1][0], c11 = ncol[j+1][1], c12 = ncol[j+1][2];
        float g00 = a00*c00 + a01*c01 + a02*c02;
        float g01 = a00*c10 + a01*c11 + a02*c12;
        float g10 = a10*c00 + a11*c01 + a12*c02;
        float g11 = a10*c10 + a11*c11 + a12*c12;
        if (tile_masked) {
            if (ew[it] == 1) { g00 = 0.0f; g11 = 0.0f; }
            if (ew[it] == 2)   g01 = 0.0f;
            if (ew[it] == 0)   g10 = 0.0f;
        }
        *(v2f*)&buf[ofs[it]]       = (v2f){g00, g01};
        *(v2f*)&buf[ofs[it] + RGP] = (v2f){g10, g11};
    }
    __syncthreads();

    // ---- 4 stencil layers, in place: compute->regs, barrier, write, barrier ----
    for (int ell = 0; ell < NLAY; ell++) {
        const float ws  = w_self[c * NLAY + ell];
        const float wn1 = w_nbr[(c * NLAY + ell) * 2 + 0];
        const float wn2 = w_nbr[(c * NLAY + ell) * 2 + 1];
        const v2f ws2 = (v2f){ws,  ws};
        const v2f w12 = (v2f){wn1, wn1};
        const v2f w22 = (v2f){wn2, wn2};
        const int pad = 2 * (ell + 1);
        v2f o0[7], o1[7];
#pragma unroll
        for (int it = 0; it < 7; it++) {
            if (ring[it] < pad) continue;
            const float* P = buf + ofs[it];
            // vertical column pairs (10 aligned b64 reads total per site)
            v2f cm2 = ld2(P - 2*RGP);
            v2f cm1 = ld2(P -   RGP);
            v2f c0  = ld2(P);
            v2f cp1 = ld2(P +   RGP);
            v2f cp2 = ld2(P + 2*RGP);
            v2f cp3 = ld2(P + 3*RGP);
            v2f A0  = ld2(P - 2);          // row i,   cols (j-2, j-1)
            v2f C0  = ld2(P + 2);          // row i,   cols (j+2, j+3)
            v2f A1  = ld2(P + RGP - 2);    // row i+1
            v2f C1  = ld2(P + RGP + 2);
            // row i: s1 = l1+r1 composed from register halves (scalar adds)
            v2f s1a; s1a.x = A0.y + c0.y;  s1a.y = c0.x + C0.x;
            v2f s2a = pk_add(A0, C0);      // l2+r2
            v2f v1a = pk_add(cm1, cp1);    // u1+d1
            v2f v2a = pk_add(cm2, cp2);    // u2+d2
            // (l+r)+(u+d): transpose site computes (u+d)+(l+r) with identical
            // operand values -> bitwise equal result
            v2f ya = pk_fma(ws2, c0, pk_fma(w12, pk_add(s1a, v1a),
                                    pk_mul(w22, pk_add(s2a, v2a))));
            // row i+1
            v2f s1b; s1b.x = A1.y + cp1.y; s1b.y = cp1.x + C1.x;
            v2f s2b = pk_add(A1, C1);
            v2f v1b = pk_add(c0,  cp2);
            v2f v2b = pk_add(cm1, cp3);
            v2f yb = pk_fma(ws2, cp1, pk_fma(w12, pk_add(s1b, v1b),
                                     pk_mul(w22, pk_add(s2b, v2b))));
            v2f xa = pk_add(c0,  celu2(ya));
            v2f xb = pk_add(cp1, celu2(yb));
            if (tile_masked) {
                if (ew[it] == 1) { xa.x = 0.0f; xb.y = 0.0f; }
                if (ew[it] == 2)   xa.y = 0.0f;
                if (ew[it] == 0)   xb.x = 0.0f;
            }
            o0[it] = xa;
            o1[it] = xb;
        }
        __syncthreads();
#pragma unroll
        for (int it = 0; it < 7; it++) {
            if (ring[it] < pad) continue;
            *(v2f*)&buf[ofs[it]]       = o0[it];
            *(v2f*)&buf[ofs[it] + RGP] = o1[it];
        }
        __syncthreads();
    }
    // final x is in buf (core = region [8,72)^2)

    // ---- cyclic-diagonal reduction: 127 diagonals, 2 threads each ----
    if (tid < 254) {
        int dt = tid >> 1;
        int half = tid & 1;
        int delta = dt - 63;                 // j - i in [-63, 63]
        int ad = delta < 0 ? -delta : delta;
        int Nd = 64 - ad;
        int i0 = 8 + (delta < 0 ? -delta : 0);
        int base = i0 * RGP + (i0 + delta);
        float s = 0.0f;
        for (int k = half; k < Nd; k += 2)
            s += buf[base + k * (RGP + 1)];
        s += __shfl_xor(s, 1);
        if (half == 0) {
            int r = (gj0 - gi0 + delta) & (LSZ - 1);
            float* sp = sep + (b * CCH + c) * LSZ;
            atomicAdd(sp + r, s);
            if (ti != tj)  // mirror contribution for the skipped transpose tile
                atomicAdd(sp + ((LSZ - r) & (LSZ - 1)), s);
        }
    }
}

// MLP stage 1 (unchanged from R5): partial[(b*32+ms)*256+k]
__global__ __launch_bounds__(256) void mlp1_kernel(
    const float* __restrict__ sep,
    const float* __restrict__ W1,
    float* __restrict__ partial)
{
    __shared__ float4 red[4][64];
    const int b  = blockIdx.x >> 5;
    const int ms = blockIdx.x & 31;
    const int kq = threadIdx.x & 63;
    const int mq = threadIdx.x >> 6;
    const int m0 = ms * 64 + mq * 16;
    const float* sv = sep + b * 2048 + m0;
    const float* w  = W1 + m0 * 256 + kq * 4;
    float4 a0 = {0,0,0,0}, a1 = {0,0,0,0};
#pragma unroll
    for (int m = 0; m < 16; m += 2) {
        float4 w0 = *(const float4*)(w + (m)     * 256);
        float4 w1 = *(const float4*)(w + (m + 1) * 256);
        float s0 = sv[m], s1 = sv[m + 1];
        a0.x += s0 * w0.x; a0.y += s0 * w0.y; a0.z += s0 * w0.z; a0.w += s0 * w0.w;
        a1.x += s1 * w1.x; a1.y += s1 * w1.y; a1.z += s1 * w1.z; a1.w += s1 * w1.w;
    }
    float4 a;
    a.x = a0.x + a1.x; a.y = a0.y + a1.y; a.z = a0.z + a1.z; a.w = a0.w + a1.w;
    red[mq][kq] = a;
    __syncthreads();
    if (mq == 0) {
        float4 r0 = red[0][kq], r1 = red[1][kq], r2 = red[2][kq], r3 = red[3][kq];
        float4 o;
        o.x = (r0.x + r1.x) + (r2.x + r3.x);
        o.y = (r0.y + r1.y) + (r2.y + r3.y);
        o.z = (r0.z + r1.z) + (r2.z + r3.z);
        o.w = (r0.w + r1.w) + (r2.w + r3.w);
        *(float4*)&partial[(b * 32 + ms) * 256 + kq * 4] = o;
    }
}

// MLP stage 2 (unchanged from R5)
__global__ __launch_bounds__(256) void mlp2_kernel(
    const float* __restrict__ partial,
    const float* __restrict__ b1,
    const float* __restrict__ W2,
    const float* __restrict__ b2,
    float* __restrict__ out)
{
    __shared__ double red[4];
    const int b = blockIdx.x;
    const int k = threadIdx.x;
    double s = 0;
#pragma unroll
    for (int p = 0; p < 32; p++)
        s += (double)partial[(b * 32 + p) * 256 + k];
    s += (double)b1[k];
    s = s >= 0.0 ? s : exp(s) - 1.0;          // celu
    double q = s * (double)W2[k];
    for (int off = 32; off >= 1; off >>= 1) q += __shfl_down(q, off);
    if ((k & 63) == 0) red[k >> 6] = q;
    __syncthreads();
    if (k == 0) {
        double y = ((red[0] + red[1]) + (red[2] + red[3])) + (double)b2[0];
        out[b] = (float)exp(-y);
    }
}

extern "C" void kernel_launch(void* const* d_in, const int* in_sizes, int n_in,
                              void* d_out, int out_size, void* d_ws, size_t ws_size,
                              hipStream_t stream) {
    const float* nn     = (const float*)d_in[0];
    const float* w_self = (const float*)d_in[1];
    const float* w_nbr  = (const float*)d_in[2];
    const float* W1     = (const float*)d_in[3];
    const float* b1     = (const float*)d_in[4];
    const float* W2     = (const float*)d_in[5];
    const float* b2     = (const float*)d_in[6];
    float* out = (float*)d_out;
    float* sep     = (float*)d_ws;                                  // 128 KB
    float* partial = (float*)((char*)d_ws + 16 * CCH * LSZ * sizeof(float)); // 512 KB

    hipMemsetAsync(sep, 0, 16 * CCH * LSZ * sizeof(float), stream);
    stencil_kernel<<<64 * 36, 256, 0, stream>>>(nn, w_self, w_nbr, sep);
    mlp1_kernel<<<512, 256, 0, stream>>>(sep, W1, partial);
    mlp2_kernel<<<16, 256, 0, stream>>>(partial, b1, W2, b2, out);
}